// Round 13
// baseline (211.220 us; speedup 1.0000x reference)
//
#include <hip/hip_runtime.h>
#include <math.h>

typedef unsigned short ush;
typedef short short8 __attribute__((ext_vector_type(8)));
typedef int i32x4 __attribute__((ext_vector_type(4)));
typedef int i32x16 __attribute__((ext_vector_type(16)));
typedef float f32x16 __attribute__((ext_vector_type(16)));
typedef unsigned int u32;

namespace {
constexpr int B = 4, C = 256, N = 4096, NCH = 4;
constexpr size_t PL8 = (size_t)B * N * C;              // 4 MB
constexpr size_t OFF_TH  = 0;
constexpr size_t OFF_TL  = PL8;
constexpr size_t OFF_PH  = 2 * PL8;
constexpr size_t OFF_PLO = 3 * PL8;
constexpr size_t OFF_G   = 4 * PL8;                    // bf16 frag-G [B][2MB]
constexpr size_t FOFF    = 4 * PL8 + (size_t)B * C * N * 2;  // 24 MB
constexpr size_t F_PM = 0;
constexpr size_t F_PS = (size_t)B * NCH * N;

// optional fast-proj region (used only if ws_size large enough)
constexpr size_t OFF_XH = 26ull * 1024 * 1024;         // bf16 [B][N][C], 8 MB
constexpr size_t OFF_XL = OFF_XH + (size_t)B * N * C * 2;
constexpr size_t OFF_WH = OFF_XL + (size_t)B * N * C * 2;   // bf16 [3][C][C]
constexpr size_t OFF_WL = OFF_WH + (size_t)3 * C * C * 2;
constexpr size_t WS_NEED = OFF_WL + (size_t)3 * C * C * 2;  // ~42.8 MB

constexpr float SCL = 8.0f / 127.0f;
constexpr float S2  = SCL * SCL;
constexpr float RB  = 1.5f / 89.09545f;
constexpr float L2E = 1.44269504f;                     // log2(e)
constexpr float BA2  = 2.0f * S2 * L2E;                // bias consts pre-scaled by log2e
constexpr float BBC2 = RB * S2 * L2E;
constexpr float C1  = 1.0f / 254.0f;
constexpr float INV_SCL = 127.0f / 8.0f;
}

#define MFMAI8(a, b, c)  __builtin_amdgcn_mfma_i32_32x32x32_i8((a), (b), (c), 0, 0, 0)
#define MFMABF(a, b, c)  __builtin_amdgcn_mfma_f32_32x32x16_bf16((a), (b), (c), 0, 0, 0)

__device__ __forceinline__ float fast_exp2(float x) {
#if __has_builtin(__builtin_amdgcn_exp2f)
  return __builtin_amdgcn_exp2f(x);
#else
  float r; asm("v_exp_f32 %0, %1" : "=v"(r) : "v"(x)); return r;
#endif
}
__device__ __forceinline__ float fast_sqrt(float x) {
#if __has_builtin(__builtin_amdgcn_sqrtf)
  return __builtin_amdgcn_sqrtf(x);
#else
  float r; asm("v_sqrt_f32 %0, %1" : "=v"(r) : "v"(x)); return r;
#endif
}

__device__ __forceinline__ ush f2bf(float v) {
  u32 x = __float_as_uint(v);
  return (ush)((x + 0x7FFFu + ((x >> 16) & 1u)) >> 16);
}
__device__ __forceinline__ float bf2f(ush h) {
  return __uint_as_float(((u32)h) << 16);
}

// shared by stats & out: MUST produce bit-identical results in both kernels.
__device__ __forceinline__ float score_i(int hh, int xx, int d2i) {
  float u = fmaf((float)xx, C1, (float)hh);
  float d = fast_sqrt((float)d2i);
  return fmaf(d, -BBC2, BA2) * u;
}

__device__ __forceinline__ void gload16(const void* g, void* l) {
  __builtin_amdgcn_global_load_lds(
      (const __attribute__((address_space(1))) u32*)(g),
      (__attribute__((address_space(3))) u32*)(l), 16, 0, 0);
}

// FRAG layout for theta/phi planes (per batch, 1 MB, bijective permutation):
// addr(m,k) = (m>>5)*8192 + (k>>5)*1024 + ((k>>4)&1)*512 + (m&31)*16 + (k&15)
// FRAG-G layout (per batch, 2 MB, bf16; ms = m>>3 is the 16-byte m-slice):
// addr(c,m) = ((c>>5)*512 + (m>>3))*512 + (c&31)*16 + (m&7)*2
// A wave's PV B-fragment (32 c-rows x 16B of m) is 1KB contiguous.

// ---------------- kernel 1 (legacy fallback): fp32 projections --------------
__global__ __launch_bounds__(256) void proj_kernel(
    const float* __restrict__ x, const float* __restrict__ w_phi,
    const float* __restrict__ w_theta, const float* __restrict__ w_g,
    char* __restrict__ wsu8) {
  __shared__ float Wst[16][68];
  __shared__ float Xs[16][68];
  const int tid = threadIdx.x, tx = tid & 15, ty = tid >> 4;
  const int b = blockIdx.y / 3, p = blockIdx.y % 3;
  const int c0 = (blockIdx.x >> 6) * 64;
  const int nb = (blockIdx.x & 63) * 64;
  const float* w = (p == 0) ? w_theta : (p == 1) ? w_phi : w_g;

  float acc[4][4] = {};
  for (int kk = 0; kk < C; kk += 16) {
    {
      int r = tid >> 2, kq = (tid & 3) << 2;
      float4 v = *reinterpret_cast<const float4*>(&w[(size_t)(c0 + r) * C + kk + kq]);
      Wst[kq + 0][r] = v.x; Wst[kq + 1][r] = v.y;
      Wst[kq + 2][r] = v.z; Wst[kq + 3][r] = v.w;
    }
    {
      int k = tid >> 4, j4 = (tid & 15) << 2;
      *reinterpret_cast<float4*>(&Xs[k][j4]) =
          *reinterpret_cast<const float4*>(&x[((size_t)b * C + kk + k) * N + nb + j4]);
    }
    __syncthreads();
#pragma unroll
    for (int k2 = 0; k2 < 16; ++k2) {
      float4 av = *reinterpret_cast<const float4*>(&Wst[k2][ty << 2]);
      float4 bv = *reinterpret_cast<const float4*>(&Xs[k2][tx << 2]);
      float aa[4] = {av.x, av.y, av.z, av.w};
      float bb[4] = {bv.x, bv.y, bv.z, bv.w};
#pragma unroll
      for (int i = 0; i < 4; ++i)
#pragma unroll
        for (int j = 0; j < 4; ++j) acc[i][j] = fmaf(aa[i], bb[j], acc[i][j]);
    }
    __syncthreads();
  }

  if (p < 2) {
    char* hi = wsu8 + (p == 0 ? OFF_TH : OFF_PH) + (size_t)b * N * C;
    char* lo = wsu8 + (p == 0 ? OFF_TL : OFF_PLO) + (size_t)b * N * C;
    const int k0 = c0 + (ty << 2);
    const size_t koff = (size_t)(k0 >> 5) * 1024 + ((k0 >> 4) & 1) * 512 + (k0 & 15);
#pragma unroll
    for (int j = 0; j < 4; ++j) {
      int n = nb + (tx << 2) + j;
      u32 ph = 0, pl = 0;
#pragma unroll
      for (int i = 0; i < 4; ++i) {
        float t = acc[i][j] * INV_SCL;
        int h = __float2int_rn(t);
        h = max(-127, min(127, h));
        int l = __float2int_rn((t - (float)h) * 254.0f);
        l = max(-127, min(127, l));
        ph |= ((u32)(h & 0xFF)) << (8 * i);
        pl |= ((u32)(l & 0xFF)) << (8 * i);
      }
      size_t a = (size_t)(n >> 5) * 8192 + (size_t)(n & 31) * 16 + koff;
      *(u32*)(hi + a) = ph;
      *(u32*)(lo + a) = pl;
    }
  } else {
    char* gp = wsu8 + OFF_G + (size_t)b * C * N * 2;
    const int n4 = nb + (tx << 2);
#pragma unroll
    for (int i = 0; i < 4; ++i) {
      int c = c0 + (ty << 2) + i;
      ushort4 pk;
      pk.x = f2bf(acc[i][0]); pk.y = f2bf(acc[i][1]);
      pk.z = f2bf(acc[i][2]); pk.w = f2bf(acc[i][3]);
      size_t a = ((size_t)(c >> 5) * 512 + (n4 >> 3)) * 512 + (c & 31) * 16 + (n4 & 7) * 2;
      *reinterpret_cast<ushort4*>(gp + a) = pk;
    }
  }
}

// ---------------- fast proj path: split kernels + MFMA GEMM ----------------
__global__ __launch_bounds__(256) void split_x(
    const float* __restrict__ x, char* __restrict__ wsu8) {
  __shared__ float Ls[64 * 66];
  const int tid = threadIdx.x;
  const int n0 = blockIdx.x * 64, c0 = blockIdx.y * 64, b = blockIdx.z;
  const float* xb = x + ((size_t)b * C + c0) * N + n0;
#pragma unroll
  for (int i = 0; i < 4; ++i) {
    int fi = i * 256 + tid, cc = fi >> 4, c4 = fi & 15;
    float4 v = *reinterpret_cast<const float4*>(xb + (size_t)cc * N + c4 * 4);
    Ls[cc * 66 + c4 * 4 + 0] = v.x; Ls[cc * 66 + c4 * 4 + 1] = v.y;
    Ls[cc * 66 + c4 * 4 + 2] = v.z; Ls[cc * 66 + c4 * 4 + 3] = v.w;
  }
  __syncthreads();
  ush* XH = (ush*)(wsu8 + OFF_XH) + ((size_t)b * N + n0) * C + c0;
  ush* XL = (ush*)(wsu8 + OFF_XL) + ((size_t)b * N + n0) * C + c0;
#pragma unroll
  for (int i = 0; i < 4; ++i) {
    int oi = i * 256 + tid, n = oi >> 4, c4 = oi & 15;
    ushort4 hv, lv;
#pragma unroll
    for (int j = 0; j < 4; ++j) {
      float v = Ls[(c4 * 4 + j) * 66 + n];
      ush h = f2bf(v);
      ush l = f2bf(v - bf2f(h));
      (&hv.x)[j] = h; (&lv.x)[j] = l;
    }
    *reinterpret_cast<ushort4*>(XH + (size_t)n * C + c4 * 4) = hv;
    *reinterpret_cast<ushort4*>(XL + (size_t)n * C + c4 * 4) = lv;
  }
}

__global__ __launch_bounds__(256) void split_w(
    const float* __restrict__ w_phi, const float* __restrict__ w_theta,
    const float* __restrict__ w_g, char* __restrict__ wsu8) {
  int id = blockIdx.x * 256 + threadIdx.x;        // 0..49151, 4 elems each
  int p = id / 16384, e4 = id % 16384;
  const float* w = (p == 0) ? w_theta : (p == 1) ? w_phi : w_g;
  float4 v = *reinterpret_cast<const float4*>(w + (size_t)e4 * 4);
  ush* WH = (ush*)(wsu8 + OFF_WH) + (size_t)p * C * C + (size_t)e4 * 4;
  ush* WL = (ush*)(wsu8 + OFF_WL) + (size_t)p * C * C + (size_t)e4 * 4;
  ushort4 hv, lv;
  float vv[4] = {v.x, v.y, v.z, v.w};
#pragma unroll
  for (int j = 0; j < 4; ++j) {
    ush h = f2bf(vv[j]);
    ush l = f2bf(vv[j] - bf2f(h));
    (&hv.x)[j] = h; (&lv.x)[j] = l;
  }
  *reinterpret_cast<ushort4*>(WH) = hv;
  *reinterpret_cast<ushort4*>(WL) = lv;
}

// MFMA projection: D[64d x 128n] = W[d][k] * X^T ([n][k] planes), K=256.
__global__ __launch_bounds__(512) void proj_mfma(char* __restrict__ wsu8) {
  __shared__ __align__(16) char plds[131072];
  const int tid = threadIdx.x, lane = tid & 63, w = tid >> 6;
  const int l31 = lane & 31, lh5 = lane >> 5;
  const int wr = w >> 2, wc = w & 3;
  const int bx = blockIdx.x;
  const int db = (bx >> 5) * 64, nb = (bx & 31) * 128;
  const int b = blockIdx.y / 3, p = blockIdx.y % 3;
  const char* xh = wsu8 + OFF_XH + (size_t)b * N * C * 2;
  const char* xl = wsu8 + OFF_XL + (size_t)b * N * C * 2;
  const char* wh = wsu8 + OFF_WH + (size_t)p * C * C * 2;
  const char* wl = wsu8 + OFF_WL + (size_t)p * C * C * 2;
  char* const Wb = plds;             // [2 planes][64 rows x 512B]
  char* const Xb = plds + 65536;     // [2 buf][2 planes][128 rows x 128B]

#pragma unroll
  for (int cix = 0; cix < 8; ++cix) {
    int pl = cix >> 2, ci = cix & 3;
    int glin = ci * 512 + tid;
    int d = glin >> 5, g = glin & 31;
    const char* src = (pl ? wl : wh) + (size_t)(db + d) * 512 + ((g ^ (d & 15)) << 4);
    gload16(src, Wb + pl * 32768 + ci * 8192 + (tid << 4));
  }
  auto stageX = [&](int ch, int buf) {
#pragma unroll
    for (int cix = 0; cix < 4; ++cix) {
      int pl = cix >> 1, ci = cix & 1;
      int glin = ci * 512 + tid;
      int n = glin >> 3, g = glin & 7;
      const char* src = (pl ? xl : xh) +
          (size_t)(nb + n) * 512 + ch * 128 + ((g ^ (n & 7)) << 4);
      gload16(src, Xb + buf * 32768 + pl * 16384 + ci * 8192 + (tid << 4));
    }
  };
  stageX(0, 0);
  __syncthreads();

  const int arow = wr * 32 + l31;    // d-row in tile
  const int brow = wc * 32 + l31;    // n-row in tile
  f32x16 acc = {};
  for (int ch = 0; ch < 4; ++ch) {
    if (ch < 3) stageX(ch + 1, (ch + 1) & 1);
    const char* XB = Xb + (ch & 1) * 32768;
    __builtin_amdgcn_s_setprio(1);
#pragma unroll
    for (int kt = 0; kt < 4; ++kt) {
      int slw = (ch * 4 + kt) * 2 + lh5;
      int oW = ((slw ^ (arow & 15)) << 4);
      short8 wa = *(const short8*)(Wb + arow * 512 + oW);
      short8 wb2 = *(const short8*)(Wb + 32768 + arow * 512 + oW);
      int slx = kt * 2 + lh5;
      int oX = ((slx ^ (brow & 7)) << 4);
      short8 xa = *(const short8*)(XB + brow * 128 + oX);
      short8 xb2 = *(const short8*)(XB + 16384 + brow * 128 + oX);
      acc = MFMABF(wa, xa, acc);
      acc = MFMABF(wa, xb2, acc);
      acc = MFMABF(wb2, xa, acc);
    }
    __builtin_amdgcn_s_setprio(0);
    __syncthreads();
  }

  const int n = nb + wc * 32 + l31;
  if (p < 2) {
    char* hi = wsu8 + (p == 0 ? OFF_TH : OFF_PH) + (size_t)b * N * C;
    char* lo = wsu8 + (p == 0 ? OFF_TL : OFF_PLO) + (size_t)b * N * C;
#pragma unroll
    for (int q = 0; q < 4; ++q) {
      u32 phv = 0, plv = 0;
#pragma unroll
      for (int j = 0; j < 4; ++j) {
        float t = acc[q * 4 + j] * INV_SCL;
        int h = __float2int_rn(t);
        h = max(-127, min(127, h));
        int l = __float2int_rn((t - (float)h) * 254.0f);
        l = max(-127, min(127, l));
        phv |= ((u32)(h & 0xFF)) << (8 * j);
        plv |= ((u32)(l & 0xFF)) << (8 * j);
      }
      int dd = db + wr * 32 + 8 * q + 4 * lh5;   // k-dim of score
      size_t a = (size_t)(n >> 5) * 8192 + (size_t)(dd >> 5) * 1024 +
                 ((dd >> 4) & 1) * 512 + (size_t)(n & 31) * 16 + (dd & 15);
      *(u32*)(hi + a) = phv;
      *(u32*)(lo + a) = plv;
    }
  } else {
    char* gp = wsu8 + OFF_G + (size_t)b * C * N * 2;
#pragma unroll
    for (int r = 0; r < 16; ++r) {
      int dd = db + wr * 32 + (r & 3) + 8 * (r >> 2) + 4 * lh5;   // c
      size_t a = ((size_t)(dd >> 5) * 512 + (n >> 3)) * 512 + (dd & 31) * 16 + (n & 7) * 2;
      *(ush*)(gp + a) = f2bf(acc[r]);
    }
  }
}

// ---------------- kernel 2: column-softmax stats, 2 blocks/CU --------------
// frag layout: all LDS stages are linear copies; all reads conflict-free.
__global__ __launch_bounds__(512, 4) void stats_kernel(
    const char* __restrict__ wsu8, float* __restrict__ fws) {
  __shared__ __align__(16) char lds[65536];
  const int tid = threadIdx.x, lane = tid & 63, w = tid >> 6;
  const int l31 = lane & 31, lh5 = lane >> 5;
  const int wr = w >> 2, wc = w & 3;
  int flat = (blockIdx.z * NCH + blockIdx.y) * 32 + blockIdx.x;
  int nf = ((flat & 7) << 6) | (flat >> 3);   // XCD swizzle (512 = 8*64)
  const int b = nf >> 7, rem = nf & 127, chunk = rem >> 5, mt = rem & 31;
  const int mb = mt * 128, cbase = chunk * 1024;
  const size_t bo = (size_t)b * N * C;
  const char* th  = wsu8 + OFF_TH + bo;
  const char* tl  = wsu8 + OFF_TL + bo;
  const char* ph  = wsu8 + OFF_PH + bo;
  const char* plo = wsu8 + OFF_PLO + bo;

  const int brow = wc * 32 + l31;      // phi row (m-local), 0..127
  i32x4 FH[8];
  {
    const char* prh = ph + (size_t)((mb >> 5) + wc) * 8192 + lh5 * 512 + l31 * 16;
#pragma unroll
    for (int q = 0; q < 8; ++q) FH[q] = *(const i32x4*)(prh + q * 1024);
  }
#pragma unroll
  for (int i = 0; i < 4; ++i)
    gload16(plo + (size_t)(mb >> 5) * 8192 + i * 8192 + tid * 16,
            lds + i * 8192 + tid * 16);
  char* const T0 = lds + 32768;
  char* const T1 = lds + 49152;

  auto stage = [&](int s, char* dst) {
    int ntx = s >> 1, h = s & 1;
    int g2 = tid >> 8;                 // 0..1 (row-group)
    int inr = (tid & 255) * 16;
#pragma unroll
    for (int plane = 0; plane < 2; ++plane) {
      const char* src = (plane ? tl : th) +
          (size_t)((cbase >> 5) + ntx * 2 + g2) * 8192 + h * 4096 + inr;
      gload16(src, dst + plane * 8192 + g2 * 4096 + inr);
    }
  };
  stage(0, T0);
  __syncthreads();

  const int m = mb + brow;
  const int mcl = m & 63, mh = m >> 6;
  const int nbl = wr * 32;
  float rmax = -3e38f, rsum = 0.0f;

  u32 dxp[8];
#pragma unroll
  for (int r2 = 0; r2 < 8; ++r2) {
    int r0i = 2 * r2, r1i = 2 * r2 + 1;
    int p0 = (r0i & 3) + 8 * (r0i >> 2) + 4 * lh5;
    int p1 = (r1i & 3) + 8 * (r1i >> 2) + 4 * lh5;
    int d0 = nbl + p0 - mcl, d1 = nbl + p1 - mcl;
    dxp[r2] = (u32)(d0 * d0) | ((u32)(d1 * d1) << 16);
  }

  char* Tc = T0; char* Tn = T1;
  for (int nt = 0; nt < 16; ++nt) {
    i32x16 HH = {}, XX = {};
#pragma unroll
    for (int h = 0; h < 2; ++h) {
      int p = nt * 2 + h;
      if (p < 31) stage(p + 1, Tn);
      __builtin_amdgcn_s_setprio(1);
#pragma unroll
      for (int kt = 0; kt < 4; ++kt) {
        int g = h * 4 + kt;
        const char* aB = Tc + wr * 4096 + kt * 1024 + lh5 * 512 + l31 * 16;
        i32x4 ah = *(const i32x4*)(aB);
        i32x4 al = *(const i32x4*)(aB + 8192);
        i32x4 bl = *(const i32x4*)(lds + wc * 8192 + g * 1024 + lh5 * 512 + l31 * 16);
        HH = MFMAI8(ah, FH[g], HH);
        XX = MFMAI8(ah, bl, XX);
        XX = MFMAI8(al, FH[g], XX);
      }
      __builtin_amdgcn_s_setprio(0);
      if (h == 1) {
        int dyi = (cbase >> 6) + nt - mh;
        int dy2i = dyi * dyi;
        float bs[16];
#pragma unroll
        for (int r = 0; r < 16; ++r) {
          int d2i = (int)((dxp[r >> 1] >> ((r & 1) * 16)) & 0xFFFFu) + dy2i;
          bs[r] = score_i(HH[r], XX[r], d2i);
        }
        float m0 = fmaxf(fmaxf(fmaxf(bs[0], bs[1]), fmaxf(bs[2], bs[3])),
                         fmaxf(fmaxf(bs[4], bs[5]), fmaxf(bs[6], bs[7])));
        float m1 = fmaxf(fmaxf(fmaxf(bs[8], bs[9]), fmaxf(bs[10], bs[11])),
                         fmaxf(fmaxf(bs[12], bs[13]), fmaxf(bs[14], bs[15])));
        float nm = fmaxf(rmax, fmaxf(m0, m1));
#pragma unroll
        for (int r = 0; r < 16; ++r) bs[r] = fast_exp2(bs[r] - nm);
        float s0 = ((bs[0] + bs[1]) + (bs[2] + bs[3])) + ((bs[4] + bs[5]) + (bs[6] + bs[7]));
        float s1 = ((bs[8] + bs[9]) + (bs[10] + bs[11])) + ((bs[12] + bs[13]) + (bs[14] + bs[15]));
        rsum = fmaf(rsum, fast_exp2(rmax - nm), s0 + s1);
        rmax = nm;
      }
      __syncthreads();
      char* t = Tc; Tc = Tn; Tn = t;
    }
  }
  {
    float om = __shfl_xor(rmax, 32);
    float os = __shfl_xor(rsum, 32);
    float nm = fmaxf(rmax, om);
    rsum = rsum * fast_exp2(rmax - nm) + os * fast_exp2(om - nm);
    rmax = nm;
  }
  float* redM = (float*)lds;            // [2][128]
  float* redS = (float*)(lds + 1024);
  if (lane < 32) {
    redM[wr * 128 + wc * 32 + l31] = rmax;
    redS[wr * 128 + wc * 32 + l31] = rsum;
  }
  __syncthreads();
  if (tid < 128) {
    float m0 = redM[tid], m1 = redM[128 + tid];
    float nm = fmaxf(m0, m1);
    float s = redS[tid] * fast_exp2(m0 - nm) + redS[128 + tid] * fast_exp2(m1 - nm);
    fws[F_PM + ((size_t)(b * NCH + chunk)) * N + mb + tid] = nm;
    fws[F_PS + ((size_t)(b * NCH + chunk)) * N + mb + tid] = s;
  }
}

// ---------------- kernel 4: scores + softmax + PV, G in registers -----------
// Phase A: full-K scores (phi frag LDS reads) + softmax -> Pb.  Phase B: PV
// with G fragments in REGISTERS (wave-private, coalesced 1KB frag-G loads) +
// phi(mc+1) stage + G(mc+1) reg prefetch. 2 barriers/mc (was 4); no G LDS.
// LDS: phi dbuf 2x64K [0,128K), Pb[128K,144K), Qb[144K,160K) = 160 KiB.
__global__ __launch_bounds__(512, 1) void out_kernel(
    const float* __restrict__ x, float* __restrict__ out,
    const char* __restrict__ wsu8, const float* __restrict__ fws) {
  __shared__ __align__(16) char lds[163840];
  const int tid = threadIdx.x, lane = tid & 63, w = tid >> 6;
  const int l31 = lane & 31, lh5 = lane >> 5;
  const int wn = w >> 2, wm = w & 3;   // score wave tile: [wn*32 n][wm*32 m]
  int flat = blockIdx.y * gridDim.x + blockIdx.x;
  int nf = ((flat & 7) << 5) | (flat >> 3);   // XCD swizzle (256 = 8*32)
  const int b = nf >> 6, ntile = nf & 63;
  const int n0 = ntile * 64;
  const size_t bo = (size_t)b * N * C;
  const char* th  = wsu8 + OFF_TH + bo;
  const char* tl  = wsu8 + OFF_TL + bo;
  const char* ph  = wsu8 + OFF_PH + bo;
  const char* plo = wsu8 + OFF_PLO + bo;
  const char* GPB = wsu8 + OFF_G + (size_t)b * C * N * 2;  // frag-G bytes

  char* const Pb = lds + 131072;
  char* const Qb = lds + 147456;

  const int pcol = wm * 32 + l31;            // this lane's m (mod 128)
  const int mcl = pcol & 63;                 // m&63: const across mc (stride 128)

  // resident theta fragments (A operand) -> registers, coalesced frag loads
  i32x4 TH[8], TL[8];
  {
    const char* trh = th + (size_t)((n0 >> 5) + wn) * 8192 + lh5 * 512 + l31 * 16;
    const char* trl = tl + (size_t)((n0 >> 5) + wn) * 8192 + lh5 * 512 + l31 * 16;
#pragma unroll
    for (int q = 0; q < 8; ++q) {
      TH[q] = *(const i32x4*)(trh + q * 1024);
      TL[q] = *(const i32x4*)(trl + q * 1024);
    }
  }
  u32 dxp[8];
#pragma unroll
  for (int r2 = 0; r2 < 8; ++r2) {
    int r0i = 2 * r2, r1i = 2 * r2 + 1;
    int p0i = wn * 32 + (r0i & 3) + 8 * (r0i >> 2) + 4 * lh5;
    int p1i = wn * 32 + (r1i & 3) + 8 * (r1i >> 2) + 4 * lh5;
    int d0 = p0i - mcl, d1 = p1i - mcl;
    dxp[r2] = (u32)(d0 * d0) | ((u32)(d1 * d1) << 16);
  }
  // compute Q[4096] from partial stats -> Qb (folded finalize_stats)
  {
    const float* PM = fws + F_PM + (size_t)b * NCH * N;
    const float* PS = fws + F_PS + (size_t)b * NCH * N;
    const int m8 = tid * 8;
    float4 pm[NCH][2], ps[NCH][2];
#pragma unroll
    for (int ch = 0; ch < NCH; ++ch) {
      pm[ch][0] = *reinterpret_cast<const float4*>(PM + (size_t)ch * N + m8);
      pm[ch][1] = *reinterpret_cast<const float4*>(PM + (size_t)ch * N + m8 + 4);
      ps[ch][0] = *reinterpret_cast<const float4*>(PS + (size_t)ch * N + m8);
      ps[ch][1] = *reinterpret_cast<const float4*>(PS + (size_t)ch * N + m8 + 4);
    }
    float qv[8];
#pragma unroll
    for (int j = 0; j < 8; ++j) {
      int h = j >> 2, e = j & 3;
      float M = fmaxf(fmaxf((&pm[0][h].x)[e], (&pm[1][h].x)[e]),
                      fmaxf((&pm[2][h].x)[e], (&pm[3][h].x)[e]));
      float S = 0.0f;
#pragma unroll
      for (int ch = 0; ch < NCH; ++ch)
        S += (&ps[ch][h].x)[e] * fast_exp2((&pm[ch][h].x)[e] - M);
      qv[j] = M + __log2f(S);
    }
    *reinterpret_cast<float4*>(Qb + m8 * 4) = make_float4(qv[0], qv[1], qv[2], qv[3]);
    *reinterpret_cast<float4*>(Qb + m8 * 4 + 16) = make_float4(qv[4], qv[5], qv[6], qv[7]);
  }

  // stagePhi: frag-layout linear copies into one 32K half-region.
  auto stagePhi = [&](int m0p, int h, char* dst) {
#pragma unroll
    for (int cix = 0; cix < 4; ++cix) {
      int p2 = cix >> 1, mpair = cix & 1;
      int mb2 = mpair * 2 + (tid >> 8);      // 0..3, wave-uniform
      int inr = (tid & 255) * 16;
      const char* base = p2 ? plo : ph;
      const char* src = base + (size_t)((m0p >> 5) + mb2) * 8192 + h * 4096 + inr;
      gload16(src, dst + p2 * 16384 + mb2 * 4096 + inr);
    }
  };
  // G fragments (wave-private c rows) -> registers, 1KB coalesced each
  auto ldG = [&](int m0g, short8 (&GR)[8]) {
    const char* base = GPB + ((size_t)(w * 512 + (m0g >> 3) + lh5)) * 512 + l31 * 16;
#pragma unroll
    for (int q = 0; q < 8; ++q) {
      int off = ((q >> 2) * 8 + (q & 3) * 2) * 512;
      GR[q] = *(const short8*)(base + off);
    }
  };

  short8 GA[8], GB[8];
  // prologue: phi(0) both K-halves -> buf0; G(0) -> GA
  stagePhi(0, 0, lds);
  stagePhi(0, 1, lds + 32768);
  ldG(0, GA);
  __syncthreads();

  f32x16 oacc0 = {}, oacc1 = {};

  auto body = [&](int mc, short8 (&GU)[8], short8 (&GP)[8]) {
    char* const Pcur = lds + (mc & 1) * 65536;
    char* const Pnxt = lds + ((mc + 1) & 1) * 65536;
    const int m0 = mc * 128;
    const int mg = m0 + pcol;
    const float Qm = *(const float*)(Qb + 4 * mg);
    i32x16 HH = {}, XX = {};

    // ---- phase A: full-K scores from phi frags; softmax -> Pb
    __builtin_amdgcn_s_setprio(1);
#pragma unroll
    for (int kt = 0; kt < 8; ++kt) {
      const char* bB = Pcur + (kt >> 2) * 32768 + wm * 4096 + (kt & 3) * 1024 +
                       lh5 * 512 + l31 * 16;
      i32x4 bh = *(const i32x4*)(bB);
      i32x4 bl = *(const i32x4*)(bB + 16384);
      HH = MFMAI8(TH[kt], bh, HH);
      XX = MFMAI8(TH[kt], bl, XX);
      XX = MFMAI8(TL[kt], bh, XX);
    }
    __builtin_amdgcn_s_setprio(0);
    {
      const int gP = pcol >> 3, bP = (pcol & 7) << 1;
      int dyi = ntile - (mg >> 6);
      int dy2i = dyi * dyi;
#pragma unroll
      for (int r = 0; r < 16; ++r) {
        int prow = wn * 32 + (r & 3) + 8 * (r >> 2) + 4 * lh5;
        int d2i = (int)((dxp[r >> 1] >> ((r & 1) * 16)) & 0xFFFFu) + dy2i;
        float bs = score_i(HH[r], XX[r], d2i);
        float pv = fast_exp2(bs - Qm);
        *(ush*)(Pb + prow * 256 + (((gP ^ (prow & 15)) << 4)) + bP) = f2bf(pv);
      }
    }
    __syncthreads();   // Pb visible

    // ---- phase B: stage phi(mc+1) + prefetch G(mc+1); PV from Pb x GU regs
    if (mc < 31) {
      stagePhi(m0 + 128, 0, Pnxt);
      stagePhi(m0 + 128, 1, Pnxt + 32768);
      ldG(m0 + 128, GP);
    }
    __builtin_amdgcn_s_setprio(1);
#pragma unroll
    for (int q = 0; q < 8; ++q) {
      int ms = (q >> 2) * 8 + (q & 3) * 2 + lh5;   // m-slice within 128
      short8 gb = GU[q];
      {
        short8 pa = *(const short8*)(Pb + l31 * 256 + ((ms ^ (l31 & 15)) << 4));
        oacc0 = MFMABF(pa, gb, oacc0);
      }
      {
        int ar = 32 + l31;
        short8 pa = *(const short8*)(Pb + ar * 256 + ((ms ^ (ar & 15)) << 4));
        oacc1 = MFMABF(pa, gb, oacc1);
      }
    }
    __builtin_amdgcn_s_setprio(0);
    __syncthreads();   // Pb reads done; phi(mc+1)/G(mc+1) drained by barrier
  };

#pragma unroll 1
  for (int mc2 = 0; mc2 < 16; ++mc2) {
    body(2 * mc2, GA, GB);
    body(2 * mc2 + 1, GB, GA);
  }

  // epilogue: transpose [n][c] -> [c][n] via LDS, residual, store
  float* Tr = (float*)lds;   // [256 c][65]
  const int c = w * 32 + l31;
#pragma unroll
  for (int r = 0; r < 16; ++r) {
    int crow = (r & 3) + 8 * (r >> 2) + 4 * lh5;
    Tr[c * 65 + crow] = oacc0[r];
    Tr[c * 65 + 32 + crow] = oacc1[r];
  }
  __syncthreads();
  const float* xb = x + (size_t)b * C * N;
  float* ob = out + (size_t)b * C * N;
  for (int e = tid; e < 16384; e += 512) {
    int cc = e >> 6, nl = e & 63;
    size_t idx = (size_t)cc * N + n0 + nl;
    ob[idx] = Tr[cc * 65 + nl] + xb[idx];
  }
}

extern "C" void kernel_launch(void* const* d_in, const int* in_sizes, int n_in,
                              void* d_out, int out_size, void* d_ws, size_t ws_size,
                              hipStream_t stream) {
  const float* x       = (const float*)d_in[0];
  const float* w_phi   = (const float*)d_in[1];
  const float* w_theta = (const float*)d_in[2];
  const float* w_g     = (const float*)d_in[3];
  float* out = (float*)d_out;
  char* wsu8 = (char*)d_ws;
  float* fws = (float*)(wsu8 + FOFF);

  if (ws_size >= WS_NEED) {
    split_x<<<dim3(64, 4, 4), 256, 0, stream>>>(x, wsu8);
    split_w<<<dim3(192), 256, 0, stream>>>(w_phi, w_theta, w_g, wsu8);
    proj_mfma<<<dim3(128, 12), 512, 0, stream>>>(wsu8);
  } else {
    proj_kernel<<<dim3(256, 12), 256, 0, stream>>>(x, w_phi, w_theta, w_g, wsu8);
  }
  stats_kernel<<<dim3(32, NCH, B), 512, 0, stream>>>(wsu8, fws);
  out_kernel<<<dim3(64, B), 512, 0, stream>>>(x, out, wsu8, fws);
}

// Round 14
// 201.266 us; speedup vs baseline: 1.0495x; 1.0495x over previous
//
#include <hip/hip_runtime.h>
#include <math.h>

typedef unsigned short ush;
typedef short short8 __attribute__((ext_vector_type(8)));
typedef int i32x4 __attribute__((ext_vector_type(4)));
typedef int i32x16 __attribute__((ext_vector_type(16)));
typedef float f32x16 __attribute__((ext_vector_type(16)));
typedef unsigned int u32;

namespace {
constexpr int B = 4, C = 256, N = 4096, NCH = 4;
constexpr size_t PL8 = (size_t)B * N * C;              // 4 MB
constexpr size_t OFF_TH  = 0;
constexpr size_t OFF_TL  = PL8;
constexpr size_t OFF_PH  = 2 * PL8;
constexpr size_t OFF_PLO = 3 * PL8;
constexpr size_t OFF_G   = 4 * PL8;                    // bf16 [B][C][N], 8 MB
constexpr size_t FOFF    = 4 * PL8 + (size_t)B * C * N * 2;  // 24 MB
constexpr size_t F_PM = 0;
constexpr size_t F_PS = (size_t)B * NCH * N;
constexpr size_t F_M  = 2 * (size_t)B * NCH * N;

// optional fast-proj region (used only if ws_size large enough)
constexpr size_t OFF_XH = 26ull * 1024 * 1024;         // bf16 [B][N][C], 8 MB
constexpr size_t OFF_XL = OFF_XH + (size_t)B * N * C * 2;
constexpr size_t OFF_WH = OFF_XL + (size_t)B * N * C * 2;   // bf16 [3][C][C]
constexpr size_t OFF_WL = OFF_WH + (size_t)3 * C * C * 2;
constexpr size_t WS_NEED = OFF_WL + (size_t)3 * C * C * 2;  // ~42.8 MB

constexpr float SCL = 8.0f / 127.0f;
constexpr float S2  = SCL * SCL;
constexpr float RB  = 1.5f / 89.09545f;
constexpr float L2E = 1.44269504f;                     // log2(e)
constexpr float BA2  = 2.0f * S2 * L2E;                // bias consts pre-scaled by log2e
constexpr float BBC2 = RB * S2 * L2E;
constexpr float C1  = 1.0f / 254.0f;
constexpr float INV_SCL = 127.0f / 8.0f;
}

#define MFMAI8(a, b, c)  __builtin_amdgcn_mfma_i32_32x32x32_i8((a), (b), (c), 0, 0, 0)
#define MFMABF(a, b, c)  __builtin_amdgcn_mfma_f32_32x32x16_bf16((a), (b), (c), 0, 0, 0)

// counted-vmcnt pipeline barriers: never drain to 0 in steady state
#define WAITV(n) asm volatile("s_waitcnt vmcnt(" #n ")" ::: "memory")
#define WAITVL(n) asm volatile("s_waitcnt vmcnt(" #n ") lgkmcnt(0)" ::: "memory")
#define PBAR __builtin_amdgcn_s_barrier()

__device__ __forceinline__ float fast_exp2(float x) {
#if __has_builtin(__builtin_amdgcn_exp2f)
  return __builtin_amdgcn_exp2f(x);
#else
  float r; asm("v_exp_f32 %0, %1" : "=v"(r) : "v"(x)); return r;
#endif
}
__device__ __forceinline__ float fast_sqrt(float x) {
#if __has_builtin(__builtin_amdgcn_sqrtf)
  return __builtin_amdgcn_sqrtf(x);
#else
  float r; asm("v_sqrt_f32 %0, %1" : "=v"(r) : "v"(x)); return r;
#endif
}

__device__ __forceinline__ ush f2bf(float v) {
  u32 x = __float_as_uint(v);
  return (ush)((x + 0x7FFFu + ((x >> 16) & 1u)) >> 16);
}
__device__ __forceinline__ float bf2f(ush h) {
  return __uint_as_float(((u32)h) << 16);
}

// shared by stats & out: MUST produce bit-identical results in both kernels.
__device__ __forceinline__ float score_i(int hh, int xx, int d2i) {
  float u = fmaf((float)xx, C1, (float)hh);
  float d = fast_sqrt((float)d2i);
  return fmaf(d, -BBC2, BA2) * u;
}

__device__ __forceinline__ void gload16(const void* g, void* l) {
  __builtin_amdgcn_global_load_lds(
      (const __attribute__((address_space(1))) u32*)(g),
      (__attribute__((address_space(3))) u32*)(l), 16, 0, 0);
}

// FRAG layout for theta/phi planes (per batch, 1 MB, bijective permutation):
// addr(m,k) = (m>>5)*8192 + (k>>5)*1024 + ((k>>4)&1)*512 + (m&31)*16 + (k&15)
// A wave's MFMA fragment (32 consecutive m, 16B of k) is 1KB contiguous.

// ---------------- kernel 1 (legacy fallback): fp32 projections --------------
__global__ __launch_bounds__(256) void proj_kernel(
    const float* __restrict__ x, const float* __restrict__ w_phi,
    const float* __restrict__ w_theta, const float* __restrict__ w_g,
    char* __restrict__ wsu8) {
  __shared__ float Wst[16][68];
  __shared__ float Xs[16][68];
  const int tid = threadIdx.x, tx = tid & 15, ty = tid >> 4;
  const int b = blockIdx.y / 3, p = blockIdx.y % 3;
  const int c0 = (blockIdx.x >> 6) * 64;
  const int nb = (blockIdx.x & 63) * 64;
  const float* w = (p == 0) ? w_theta : (p == 1) ? w_phi : w_g;

  float acc[4][4] = {};
  for (int kk = 0; kk < C; kk += 16) {
    {
      int r = tid >> 2, kq = (tid & 3) << 2;
      float4 v = *reinterpret_cast<const float4*>(&w[(size_t)(c0 + r) * C + kk + kq]);
      Wst[kq + 0][r] = v.x; Wst[kq + 1][r] = v.y;
      Wst[kq + 2][r] = v.z; Wst[kq + 3][r] = v.w;
    }
    {
      int k = tid >> 4, j4 = (tid & 15) << 2;
      *reinterpret_cast<float4*>(&Xs[k][j4]) =
          *reinterpret_cast<const float4*>(&x[((size_t)b * C + kk + k) * N + nb + j4]);
    }
    __syncthreads();
#pragma unroll
    for (int k2 = 0; k2 < 16; ++k2) {
      float4 av = *reinterpret_cast<const float4*>(&Wst[k2][ty << 2]);
      float4 bv = *reinterpret_cast<const float4*>(&Xs[k2][tx << 2]);
      float aa[4] = {av.x, av.y, av.z, av.w};
      float bb[4] = {bv.x, bv.y, bv.z, bv.w};
#pragma unroll
      for (int i = 0; i < 4; ++i)
#pragma unroll
        for (int j = 0; j < 4; ++j) acc[i][j] = fmaf(aa[i], bb[j], acc[i][j]);
    }
    __syncthreads();
  }

  if (p < 2) {
    char* hi = wsu8 + (p == 0 ? OFF_TH : OFF_PH) + (size_t)b * N * C;
    char* lo = wsu8 + (p == 0 ? OFF_TL : OFF_PLO) + (size_t)b * N * C;
    const int k0 = c0 + (ty << 2);
    const size_t koff = (size_t)(k0 >> 5) * 1024 + ((k0 >> 4) & 1) * 512 + (k0 & 15);
#pragma unroll
    for (int j = 0; j < 4; ++j) {
      int n = nb + (tx << 2) + j;
      u32 ph = 0, pl = 0;
#pragma unroll
      for (int i = 0; i < 4; ++i) {
        float t = acc[i][j] * INV_SCL;
        int h = __float2int_rn(t);
        h = max(-127, min(127, h));
        int l = __float2int_rn((t - (float)h) * 254.0f);
        l = max(-127, min(127, l));
        ph |= ((u32)(h & 0xFF)) << (8 * i);
        pl |= ((u32)(l & 0xFF)) << (8 * i);
      }
      size_t a = (size_t)(n >> 5) * 8192 + (size_t)(n & 31) * 16 + koff;
      *(u32*)(hi + a) = ph;
      *(u32*)(lo + a) = pl;
    }
  } else {
    ush* gp = (ush*)(wsu8 + OFF_G) + (size_t)b * C * N;
#pragma unroll
    for (int i = 0; i < 4; ++i) {
      ushort4 pk;
      pk.x = f2bf(acc[i][0]); pk.y = f2bf(acc[i][1]);
      pk.z = f2bf(acc[i][2]); pk.w = f2bf(acc[i][3]);
      *reinterpret_cast<ushort4*>(&gp[(size_t)(c0 + (ty << 2) + i) * N + nb + (tx << 2)]) = pk;
    }
  }
}

// ---------------- fast proj path: split kernels + MFMA GEMM ----------------
__global__ __launch_bounds__(256) void split_x(
    const float* __restrict__ x, char* __restrict__ wsu8) {
  __shared__ float Ls[64 * 66];
  const int tid = threadIdx.x;
  const int n0 = blockIdx.x * 64, c0 = blockIdx.y * 64, b = blockIdx.z;
  const float* xb = x + ((size_t)b * C + c0) * N + n0;
#pragma unroll
  for (int i = 0; i < 4; ++i) {
    int fi = i * 256 + tid, cc = fi >> 4, c4 = fi & 15;
    float4 v = *reinterpret_cast<const float4*>(xb + (size_t)cc * N + c4 * 4);
    Ls[cc * 66 + c4 * 4 + 0] = v.x; Ls[cc * 66 + c4 * 4 + 1] = v.y;
    Ls[cc * 66 + c4 * 4 + 2] = v.z; Ls[cc * 66 + c4 * 4 + 3] = v.w;
  }
  __syncthreads();
  ush* XH = (ush*)(wsu8 + OFF_XH) + ((size_t)b * N + n0) * C + c0;
  ush* XL = (ush*)(wsu8 + OFF_XL) + ((size_t)b * N + n0) * C + c0;
#pragma unroll
  for (int i = 0; i < 4; ++i) {
    int oi = i * 256 + tid, n = oi >> 4, c4 = oi & 15;
    ushort4 hv, lv;
#pragma unroll
    for (int j = 0; j < 4; ++j) {
      float v = Ls[(c4 * 4 + j) * 66 + n];
      ush h = f2bf(v);
      ush l = f2bf(v - bf2f(h));
      (&hv.x)[j] = h; (&lv.x)[j] = l;
    }
    *reinterpret_cast<ushort4*>(XH + (size_t)n * C + c4 * 4) = hv;
    *reinterpret_cast<ushort4*>(XL + (size_t)n * C + c4 * 4) = lv;
  }
}

__global__ __launch_bounds__(256) void split_w(
    const float* __restrict__ w_phi, const float* __restrict__ w_theta,
    const float* __restrict__ w_g, char* __restrict__ wsu8) {
  int id = blockIdx.x * 256 + threadIdx.x;        // 0..49151, 4 elems each
  int p = id / 16384, e4 = id % 16384;
  const float* w = (p == 0) ? w_theta : (p == 1) ? w_phi : w_g;
  float4 v = *reinterpret_cast<const float4*>(w + (size_t)e4 * 4);
  ush* WH = (ush*)(wsu8 + OFF_WH) + (size_t)p * C * C + (size_t)e4 * 4;
  ush* WL = (ush*)(wsu8 + OFF_WL) + (size_t)p * C * C + (size_t)e4 * 4;
  ushort4 hv, lv;
  float vv[4] = {v.x, v.y, v.z, v.w};
#pragma unroll
  for (int j = 0; j < 4; ++j) {
    ush h = f2bf(vv[j]);
    ush l = f2bf(vv[j] - bf2f(h));
    (&hv.x)[j] = h; (&lv.x)[j] = l;
  }
  *reinterpret_cast<ushort4*>(WH) = hv;
  *reinterpret_cast<ushort4*>(WL) = lv;
}

// MFMA projection: D[64d x 128n] = W[d][k] * X^T ([n][k] planes), K=256.
__global__ __launch_bounds__(512) void proj_mfma(char* __restrict__ wsu8) {
  __shared__ __align__(16) char plds[131072];
  const int tid = threadIdx.x, lane = tid & 63, w = tid >> 6;
  const int l31 = lane & 31, lh5 = lane >> 5;
  const int wr = w >> 2, wc = w & 3;
  const int bx = blockIdx.x;
  const int db = (bx >> 5) * 64, nb = (bx & 31) * 128;
  const int b = blockIdx.y / 3, p = blockIdx.y % 3;
  const char* xh = wsu8 + OFF_XH + (size_t)b * N * C * 2;
  const char* xl = wsu8 + OFF_XL + (size_t)b * N * C * 2;
  const char* wh = wsu8 + OFF_WH + (size_t)p * C * C * 2;
  const char* wl = wsu8 + OFF_WL + (size_t)p * C * C * 2;
  char* const Wb = plds;             // [2 planes][64 rows x 512B]
  char* const Xb = plds + 65536;     // [2 buf][2 planes][128 rows x 128B]

#pragma unroll
  for (int cix = 0; cix < 8; ++cix) {
    int pl = cix >> 2, ci = cix & 3;
    int glin = ci * 512 + tid;
    int d = glin >> 5, g = glin & 31;
    const char* src = (pl ? wl : wh) + (size_t)(db + d) * 512 + ((g ^ (d & 15)) << 4);
    gload16(src, Wb + pl * 32768 + ci * 8192 + (tid << 4));
  }
  auto stageX = [&](int ch, int buf) {
#pragma unroll
    for (int cix = 0; cix < 4; ++cix) {
      int pl = cix >> 1, ci = cix & 1;
      int glin = ci * 512 + tid;
      int n = glin >> 3, g = glin & 7;
      const char* src = (pl ? xl : xh) +
          (size_t)(nb + n) * 512 + ch * 128 + ((g ^ (n & 7)) << 4);
      gload16(src, Xb + buf * 32768 + pl * 16384 + ci * 8192 + (tid << 4));
    }
  };
  stageX(0, 0);
  __syncthreads();

  const int arow = wr * 32 + l31;    // d-row in tile
  const int brow = wc * 32 + l31;    // n-row in tile
  f32x16 acc = {};
  for (int ch = 0; ch < 4; ++ch) {
    if (ch < 3) stageX(ch + 1, (ch + 1) & 1);
    const char* XB = Xb + (ch & 1) * 32768;
    __builtin_amdgcn_s_setprio(1);
#pragma unroll
    for (int kt = 0; kt < 4; ++kt) {
      int slw = (ch * 4 + kt) * 2 + lh5;
      int oW = ((slw ^ (arow & 15)) << 4);
      short8 wa = *(const short8*)(Wb + arow * 512 + oW);
      short8 wb2 = *(const short8*)(Wb + 32768 + arow * 512 + oW);
      int slx = kt * 2 + lh5;
      int oX = ((slx ^ (brow & 7)) << 4);
      short8 xa = *(const short8*)(XB + brow * 128 + oX);
      short8 xb2 = *(const short8*)(XB + 16384 + brow * 128 + oX);
      acc = MFMABF(wa, xa, acc);
      acc = MFMABF(wa, xb2, acc);
      acc = MFMABF(wb2, xa, acc);
    }
    __builtin_amdgcn_s_setprio(0);
    __syncthreads();
  }

  const int n = nb + wc * 32 + l31;
  if (p < 2) {
    char* hi = wsu8 + (p == 0 ? OFF_TH : OFF_PH) + (size_t)b * N * C;
    char* lo = wsu8 + (p == 0 ? OFF_TL : OFF_PLO) + (size_t)b * N * C;
#pragma unroll
    for (int q = 0; q < 4; ++q) {
      u32 phv = 0, plv = 0;
#pragma unroll
      for (int j = 0; j < 4; ++j) {
        float t = acc[q * 4 + j] * INV_SCL;
        int h = __float2int_rn(t);
        h = max(-127, min(127, h));
        int l = __float2int_rn((t - (float)h) * 254.0f);
        l = max(-127, min(127, l));
        phv |= ((u32)(h & 0xFF)) << (8 * j);
        plv |= ((u32)(l & 0xFF)) << (8 * j);
      }
      int dd = db + wr * 32 + 8 * q + 4 * lh5;   // k-dim of score
      size_t a = (size_t)(n >> 5) * 8192 + (size_t)(dd >> 5) * 1024 +
                 ((dd >> 4) & 1) * 512 + (size_t)(n & 31) * 16 + (dd & 15);
      *(u32*)(hi + a) = phv;
      *(u32*)(lo + a) = plv;
    }
  } else {
    ush* gp = (ush*)(wsu8 + OFF_G) + (size_t)b * C * N;
#pragma unroll
    for (int r = 0; r < 16; ++r) {
      int dd = db + wr * 32 + (r & 3) + 8 * (r >> 2) + 4 * lh5;
      gp[(size_t)dd * N + n] = f2bf(acc[r]);
    }
  }
}

// ---------------- kernel 2: column-softmax stats, 2 blocks/CU --------------
// frag layout: all LDS stages are linear copies; all reads conflict-free.
__global__ __launch_bounds__(512, 4) void stats_kernel(
    const char* __restrict__ wsu8, float* __restrict__ fws) {
  __shared__ __align__(16) char lds[65536];
  const int tid = threadIdx.x, lane = tid & 63, w = tid >> 6;
  const int l31 = lane & 31, lh5 = lane >> 5;
  const int wr = w >> 2, wc = w & 3;
  int flat = (blockIdx.z * NCH + blockIdx.y) * 32 + blockIdx.x;
  int nf = ((flat & 7) << 6) | (flat >> 3);   // XCD swizzle (512 = 8*64)
  const int b = nf >> 7, rem = nf & 127, chunk = rem >> 5, mt = rem & 31;
  const int mb = mt * 128, cbase = chunk * 1024;
  const size_t bo = (size_t)b * N * C;
  const char* th  = wsu8 + OFF_TH + bo;
  const char* tl  = wsu8 + OFF_TL + bo;
  const char* ph  = wsu8 + OFF_PH + bo;
  const char* plo = wsu8 + OFF_PLO + bo;

  const int brow = wc * 32 + l31;      // phi row (m-local), 0..127
  i32x4 FH[8];
  {
    const char* prh = ph + (size_t)((mb >> 5) + wc) * 8192 + lh5 * 512 + l31 * 16;
#pragma unroll
    for (int q = 0; q < 8; ++q) FH[q] = *(const i32x4*)(prh + q * 1024);
  }
#pragma unroll
  for (int i = 0; i < 4; ++i)
    gload16(plo + (size_t)(mb >> 5) * 8192 + i * 8192 + tid * 16,
            lds + i * 8192 + tid * 16);
  char* const T0 = lds + 32768;
  char* const T1 = lds + 49152;

  auto stage = [&](int s, char* dst) {
    int ntx = s >> 1, h = s & 1;
    int g2 = tid >> 8;                 // 0..1 (row-group)
    int inr = (tid & 255) * 16;
#pragma unroll
    for (int plane = 0; plane < 2; ++plane) {
      const char* src = (plane ? tl : th) +
          (size_t)((cbase >> 5) + ntx * 2 + g2) * 8192 + h * 4096 + inr;
      gload16(src, dst + plane * 8192 + g2 * 4096 + inr);
    }
  };
  stage(0, T0);
  __syncthreads();

  const int m = mb + brow;
  const int mcl = m & 63, mh = m >> 6;
  const int nbl = wr * 32;
  float rmax = -3e38f, rsum = 0.0f;

  u32 dxp[8];
#pragma unroll
  for (int r2 = 0; r2 < 8; ++r2) {
    int r0i = 2 * r2, r1i = 2 * r2 + 1;
    int p0 = (r0i & 3) + 8 * (r0i >> 2) + 4 * lh5;
    int p1 = (r1i & 3) + 8 * (r1i >> 2) + 4 * lh5;
    int d0 = nbl + p0 - mcl, d1 = nbl + p1 - mcl;
    dxp[r2] = (u32)(d0 * d0) | ((u32)(d1 * d1) << 16);
  }

  char* Tc = T0; char* Tn = T1;
  for (int nt = 0; nt < 16; ++nt) {
    i32x16 HH = {}, XX = {};
#pragma unroll
    for (int h = 0; h < 2; ++h) {
      int p = nt * 2 + h;
      if (p < 31) stage(p + 1, Tn);
      __builtin_amdgcn_s_setprio(1);
#pragma unroll
      for (int kt = 0; kt < 4; ++kt) {
        int g = h * 4 + kt;
        const char* aB = Tc + wr * 4096 + kt * 1024 + lh5 * 512 + l31 * 16;
        i32x4 ah = *(const i32x4*)(aB);
        i32x4 al = *(const i32x4*)(aB + 8192);
        i32x4 bl = *(const i32x4*)(lds + wc * 8192 + g * 1024 + lh5 * 512 + l31 * 16);
        HH = MFMAI8(ah, FH[g], HH);
        XX = MFMAI8(ah, bl, XX);
        XX = MFMAI8(al, FH[g], XX);
      }
      __builtin_amdgcn_s_setprio(0);
      if (h == 1) {
        int dyi = (cbase >> 6) + nt - mh;
        int dy2i = dyi * dyi;
        float bs[16];
#pragma unroll
        for (int r = 0; r < 16; ++r) {
          int d2i = (int)((dxp[r >> 1] >> ((r & 1) * 16)) & 0xFFFFu) + dy2i;
          bs[r] = score_i(HH[r], XX[r], d2i);
        }
        float m0 = fmaxf(fmaxf(fmaxf(bs[0], bs[1]), fmaxf(bs[2], bs[3])),
                         fmaxf(fmaxf(bs[4], bs[5]), fmaxf(bs[6], bs[7])));
        float m1 = fmaxf(fmaxf(fmaxf(bs[8], bs[9]), fmaxf(bs[10], bs[11])),
                         fmaxf(fmaxf(bs[12], bs[13]), fmaxf(bs[14], bs[15])));
        float nm = fmaxf(rmax, fmaxf(m0, m1));
#pragma unroll
        for (int r = 0; r < 16; ++r) bs[r] = fast_exp2(bs[r] - nm);
        float s0 = ((bs[0] + bs[1]) + (bs[2] + bs[3])) + ((bs[4] + bs[5]) + (bs[6] + bs[7]));
        float s1 = ((bs[8] + bs[9]) + (bs[10] + bs[11])) + ((bs[12] + bs[13]) + (bs[14] + bs[15]));
        rsum = fmaf(rsum, fast_exp2(rmax - nm), s0 + s1);
        rmax = nm;
      }
      __syncthreads();
      char* t = Tc; Tc = Tn; Tn = t;
    }
  }
  {
    float om = __shfl_xor(rmax, 32);
    float os = __shfl_xor(rsum, 32);
    float nm = fmaxf(rmax, om);
    rsum = rsum * fast_exp2(rmax - nm) + os * fast_exp2(om - nm);
    rmax = nm;
  }
  float* redM = (float*)lds;            // [2][128]
  float* redS = (float*)(lds + 1024);
  if (lane < 32) {
    redM[wr * 128 + wc * 32 + l31] = rmax;
    redS[wr * 128 + wc * 32 + l31] = rsum;
  }
  __syncthreads();
  if (tid < 128) {
    float m0 = redM[tid], m1 = redM[128 + tid];
    float nm = fmaxf(m0, m1);
    float s = redS[tid] * fast_exp2(m0 - nm) + redS[128 + tid] * fast_exp2(m1 - nm);
    fws[F_PM + ((size_t)(b * NCH + chunk)) * N + mb + tid] = nm;
    fws[F_PS + ((size_t)(b * NCH + chunk)) * N + mb + tid] = s;
  }
}

// ---------------- kernel 3: reduce partial stats -> Q[m] = max + log2(sum) --
__global__ __launch_bounds__(256) void finalize_stats(float* __restrict__ fws) {
  int id = blockIdx.x * 256 + threadIdx.x;
  if (id >= B * N) return;
  int b = id >> 12, m = id & (N - 1);
  float M = -3e38f;
#pragma unroll
  for (int ch = 0; ch < NCH; ++ch)
    M = fmaxf(M, fws[F_PM + (size_t)(b * NCH + ch) * N + m]);
  float S = 0.0f;
#pragma unroll
  for (int ch = 0; ch < NCH; ++ch)
    S += fws[F_PS + (size_t)(b * NCH + ch) * N + m] *
         fast_exp2(fws[F_PM + (size_t)(b * NCH + ch) * N + m] - M);
  fws[F_M + id] = M + __log2f(S);   // single fused constant Q[m]
}

// ---------------- kernel 4: scores + softmax + PV, counted-vmcnt pipeline ---
// R4 structure (3-buffer rotation, theta in regs, phi via LDS) + FRAG layout:
// stagePhi = linear 4KB copies; score ds_reads fully contiguous (0 conflicts).
// LDS: R0/R1/R2 (3x32K) Pb[96K,112K) Qb[112K,128K).
__global__ __launch_bounds__(512, 1) void out_kernel(
    const float* __restrict__ x, float* __restrict__ out,
    const char* __restrict__ wsu8, const float* __restrict__ fws) {
  __shared__ __align__(16) char lds[131072];
  const int tid = threadIdx.x, lane = tid & 63, w = tid >> 6;
  const int l31 = lane & 31, lh5 = lane >> 5;
  const int wn = w >> 2, wm = w & 3;   // score wave tile: [wn*32 n][wm*32 m]
  int flat = blockIdx.y * gridDim.x + blockIdx.x;
  int nf = ((flat & 7) << 5) | (flat >> 3);   // XCD swizzle (256 = 8*32)
  const int b = nf >> 6, ntile = nf & 63;
  const int n0 = ntile * 64;
  const size_t bo = (size_t)b * N * C;
  const char* th  = wsu8 + OFF_TH + bo;
  const char* tl  = wsu8 + OFF_TL + bo;
  const char* ph  = wsu8 + OFF_PH + bo;
  const char* plo = wsu8 + OFF_PLO + bo;
  const char* GPB = wsu8 + OFF_G + (size_t)b * C * N * 2;  // bf16 [C][N] bytes
  const float* Qv = fws + F_M + (size_t)b * N;

  char* const R0 = lds;
  char* const R1 = lds + 32768;
  char* const R2 = lds + 65536;
  char* const Pb = lds + 98304;
  char* const Qb = lds + 114688;

  const int grow = w * 32 + l31;             // G row (c)
  const int gswz = grow & 7;
  const int pcol = wm * 32 + l31;            // this lane's m (mod 128)
  const int mcl = pcol & 63;                 // m&63: const across mc (stride 128)

  // resident theta fragments (A operand) -> registers, coalesced frag loads
  i32x4 TH[8], TL[8];
  {
    const char* trh = th + (size_t)((n0 >> 5) + wn) * 8192 + lh5 * 512 + l31 * 16;
    const char* trl = tl + (size_t)((n0 >> 5) + wn) * 8192 + lh5 * 512 + l31 * 16;
#pragma unroll
    for (int q = 0; q < 8; ++q) {
      TH[q] = *(const i32x4*)(trh + q * 1024);
      TL[q] = *(const i32x4*)(trl + q * 1024);
    }
  }
  u32 dxp[8];
#pragma unroll
  for (int r2 = 0; r2 < 8; ++r2) {
    int r0i = 2 * r2, r1i = 2 * r2 + 1;
    int p0i = wn * 32 + (r0i & 3) + 8 * (r0i >> 2) + 4 * lh5;
    int p1i = wn * 32 + (r1i & 3) + 8 * (r1i >> 2) + 4 * lh5;
    int d0 = p0i - mcl, d1 = p1i - mcl;
    dxp[r2] = (u32)(d0 * d0) | ((u32)(d1 * d1) << 16);
  }
  // Q[4096] f32 -> LDS (16KB)
#pragma unroll
  for (int i = 0; i < 2; ++i)
    gload16((const char*)Qv + i * 8192 + w * 1024 + lane * 16,
            Qb + i * 8192 + w * 1024 + lane * 16);

  // stagePhi: frag-layout linear copies. dst layout: [plane 16K][mblock 4K].
  // 4 gload16/thread (vmcnt accounting identical to R4).
  auto stagePhi = [&](int m0p, int h, char* dst) {
#pragma unroll
    for (int cix = 0; cix < 4; ++cix) {
      int p2 = cix >> 1, mpair = cix & 1;
      int mb2 = mpair * 2 + (tid >> 8);      // 0..3, wave-uniform
      int inr = (tid & 255) * 16;
      const char* base = p2 ? plo : ph;
      const char* src = base + (size_t)((m0p >> 5) + mb2) * 8192 + h * 4096 + inr;
      gload16(src, dst + p2 * 16384 + mb2 * 4096 + inr);
    }
  };
  auto stageG = [&](int m0g, char* dst) {
#pragma unroll
    for (int cix = 0; cix < 4; ++cix) {
      int rl = cix * 64 + w * 8 + (lane >> 3);
      int gc = lane & 7;
      const char* src = GPB + (size_t)rl * (N * 2) + (size_t)m0g * 2 + ((gc ^ (rl & 7)) << 4);
      gload16(src, dst + cix * 8192 + w * 1024 + lane * 16);
    }
  };

  // prologue: phiK0(0)->R0, phiK1(0)->R1
  stagePhi(0, 0, R0);
  stagePhi(0, 1, R1);
  WAITV(4);            // TH/TL, Qb, phiK0 done; phiK1 may be in flight
  PBAR;

  f32x16 oacc0 = {}, oacc1 = {};
  char* Bc = R0; char* Bn = R1; char* Bn2 = R2;

  for (int mc = 0; mc < 32; ++mc) {
    const int m0 = mc * 128;
    i32x16 HH = {}, XX = {};
    const int mg = m0 + pcol;
    const float Qm = *(const float*)(Qb + 4 * mg);

    // ---- phase A: issue G0(mc)->Bn2; scoreK0 from Bc (phiK0, frag reads)
    stageG(m0, Bn2);
    __builtin_amdgcn_s_setprio(1);
#pragma unroll
    for (int kt = 0; kt < 4; ++kt) {
      const char* bB = Bc + wm * 4096 + kt * 1024 + lh5 * 512 + l31 * 16;
      i32x4 bh = *(const i32x4*)(bB);
      i32x4 bl = *(const i32x4*)(bB + 16384);
      HH = MFMAI8(TH[kt], bh, HH);
      XX = MFMAI8(TH[kt], bl, XX);
      XX = MFMAI8(TL[kt], bh, XX);
    }
    __builtin_amdgcn_s_setprio(0);
    WAITV(4); PBAR;

    // ---- phase B: issue G1(mc)->Bc; scoreK1 from Bn (phiK1); softmax -> Pb
    stageG(m0 + 64, Bc);
    __builtin_amdgcn_s_setprio(1);
#pragma unroll
    for (int kt = 0; kt < 4; ++kt) {
      const char* bB = Bn + wm * 4096 + kt * 1024 + lh5 * 512 + l31 * 16;
      i32x4 bh = *(const i32x4*)(bB);
      i32x4 bl = *(const i32x4*)(bB + 16384);
      HH = MFMAI8(TH[4 + kt], bh, HH);
      XX = MFMAI8(TH[4 + kt], bl, XX);
      XX = MFMAI8(TL[4 + kt], bh, XX);
    }
    __builtin_amdgcn_s_setprio(0);
    {
      const int gP = pcol >> 3, bP = (pcol & 7) << 1;
      int dyi = ntile - (mg >> 6);
      int dy2i = dyi * dyi;
#pragma unroll
      for (int r = 0; r < 16; ++r) {
        int prow = wn * 32 + (r & 3) + 8 * (r >> 2) + 4 * lh5;
        int d2i = (int)((dxp[r >> 1] >> ((r & 1) * 16)) & 0xFFFFu) + dy2i;
        float bs = score_i(HH[r], XX[r], d2i);
        float pv = fast_exp2(bs - Qm);
        *(ush*)(Pb + prow * 256 + (((gP ^ (prow & 15)) << 4)) + bP) = f2bf(pv);
      }
    }
    WAITVL(4); PBAR;   // G0 done; P visible

    // ---- phase C: issue phiK0(mc+1)->Bn; PV half 0 from Bn2 (G0)
    if (mc < 31) stagePhi(m0 + 128, 0, Bn);
    __builtin_amdgcn_s_setprio(1);
#pragma unroll
    for (int t2 = 0; t2 < 4; ++t2) {
      int gG = (((t2 * 2 + lh5) ^ gswz) << 4);
      short8 gb = *(const short8*)(Bn2 + grow * 128 + gG);
      {
        int gP0 = ((((t2 * 2 + lh5) ^ (l31 & 15)) << 4));
        short8 pa = *(const short8*)(Pb + l31 * 256 + gP0);
        oacc0 = MFMABF(pa, gb, oacc0);
      }
      {
        int ar = 32 + l31;
        int gP1 = ((((t2 * 2 + lh5) ^ (ar & 15)) << 4));
        short8 pa = *(const short8*)(Pb + ar * 256 + gP1);
        oacc1 = MFMABF(pa, gb, oacc1);
      }
    }
    __builtin_amdgcn_s_setprio(0);
    if (mc < 31) { WAITV(4); } else { WAITV(0); }
    PBAR;

    // ---- phase D: issue phiK1(mc+1)->Bn2; PV half 1 from Bc (G1)
    if (mc < 31) stagePhi(m0 + 128, 1, Bn2);
    __builtin_amdgcn_s_setprio(1);
#pragma unroll
    for (int t2 = 0; t2 < 4; ++t2) {
      int gG = (((t2 * 2 + lh5) ^ gswz) << 4);
      short8 gb = *(const short8*)(Bc + grow * 128 + gG);
      {
        int gP0 = ((((8 + t2 * 2 + lh5) ^ (l31 & 15)) << 4));
        short8 pa = *(const short8*)(Pb + l31 * 256 + gP0);
        oacc0 = MFMABF(pa, gb, oacc0);
      }
      {
        int ar = 32 + l31;
        int gP1 = ((((8 + t2 * 2 + lh5) ^ (ar & 15)) << 4));
        short8 pa = *(const short8*)(Pb + ar * 256 + gP1);
        oacc1 = MFMABF(pa, gb, oacc1);
      }
    }
    __builtin_amdgcn_s_setprio(0);
    if (mc < 31) { WAITV(4); } else { WAITV(0); }
    PBAR;

    char* t = Bc; Bc = Bn; Bn = Bn2; Bn2 = t;
  }

  // epilogue: transpose [n][c] -> [c][n] via LDS, residual, store
  float* Tr = (float*)lds;   // [256 c][65]
  const int c = w * 32 + l31;
#pragma unroll
  for (int r = 0; r < 16; ++r) {
    int crow = (r & 3) + 8 * (r >> 2) + 4 * lh5;
    Tr[c * 65 + crow] = oacc0[r];
    Tr[c * 65 + 32 + crow] = oacc1[r];
  }
  __syncthreads();
  const float* xb = x + (size_t)b * C * N;
  float* ob = out + (size_t)b * C * N;
  for (int e = tid; e < 16384; e += 512) {
    int cc = e >> 6, nl = e & 63;
    size_t idx = (size_t)cc * N + n0 + nl;
    ob[idx] = Tr[cc * 65 + nl] + xb[idx];
  }
}

extern "C" void kernel_launch(void* const* d_in, const int* in_sizes, int n_in,
                              void* d_out, int out_size, void* d_ws, size_t ws_size,
                              hipStream_t stream) {
  const float* x       = (const float*)d_in[0];
  const float* w_phi   = (const float*)d_in[1];
  const float* w_theta = (const float*)d_in[2];
  const float* w_g     = (const float*)d_in[3];
  float* out = (float*)d_out;
  char* wsu8 = (char*)d_ws;
  float* fws = (float*)(wsu8 + FOFF);

  if (ws_size >= WS_NEED) {
    split_x<<<dim3(64, 4, 4), 256, 0, stream>>>(x, wsu8);
    split_w<<<dim3(192), 256, 0, stream>>>(w_phi, w_theta, w_g, wsu8);
    proj_mfma<<<dim3(128, 12), 512, 0, stream>>>(wsu8);
  } else {
    proj_kernel<<<dim3(256, 12), 256, 0, stream>>>(x, w_phi, w_theta, w_g, wsu8);
  }
  stats_kernel<<<dim3(32, NCH, B), 512, 0, stream>>>(wsu8, fws);
  finalize_stats<<<dim3(B * N / 256), 256, 0, stream>>>(fws);
  out_kernel<<<dim3(64, B), 512, 0, stream>>>(x, out, wsu8, fws);
}